// Round 13
// baseline (799.329 us; speedup 1.0000x reference)
//
#include <hip/hip_runtime.h>
#include <hip/hip_fp16.h>
#include <math.h>

#define NUSERS 100000
#define NITEMS 50000
#define BATCH  64
#define ORDER  8
#define BSHIFT 9                                   // 512 rows per bucket
#define BROWS  (1 << BSHIFT)
#define NBUCKU ((NUSERS + BROWS - 1) >> BSHIFT)    // 196
#define NBUCKI ((NITEMS + BROWS - 1) >> BSHIFT)    // 98
#define CAPU 16384
#define CAPI 24576
#define S1_BLOCKS 512
#define S1_THREADS 1024
#define NREP 8
#define S1_SW(t) (((t) >> 6) & (NREP - 1))
#define S2_THREADS 1024

// ---------------------------------------------------------------------------
// R29 = resubmit of R28 (broker timeout, never ran). R28 = R27 with the
// compile fix: __builtin_nontemporal_* requires clang ext_vector types, not
// HIP_vector_type classes (int4/float4). Theory unchanged from R27: R26's
// item counters (42.5us, FETCH 96.5MB, 2.77TB/s fill == dur; no pipe >57%)
// are consistent with fill-bound OR latency-bound. Discriminate with
// (a) depth-1 idx prefetch (break idx->gather serial chain), (b) nontemporal
// on pure streams (idx, fp32 tau r/w) so they stop evicting ybuf/tauH in L2.
// Predict: item 42.5->~36 (FETCH -> 85-90MB), total -> ~660-690 (vs R25
// base 711). If ~711 with FETCH unchanged: hard fill-bound -> fp16
// recurrence state or roofline.
// ---------------------------------------------------------------------------

typedef int   iv4 __attribute__((ext_vector_type(4)));
typedef float fv4 __attribute__((ext_vector_type(4)));

struct __align__(8) Half4 { __half2 a, b; };
struct Coeffs { float v[ORDER + 1]; };

#define SLOT ((size_t)(NITEMS + 1) * BATCH)        // fp16 tau slot incl. zero row

__device__ __forceinline__ void acc_pk(float4& acc, Half4 v0, Half4 v1,
                                       Half4 v2, Half4 v3) {
    __half2 sa = __hadd2(__hadd2(v0.a, v1.a), __hadd2(v2.a, v3.a));
    __half2 sb = __hadd2(__hadd2(v0.b, v1.b), __hadd2(v2.b, v3.b));
    float2 fa = __half22float2(sa);
    float2 fb = __half22float2(sb);
    acc.x += fa.x; acc.y += fa.y; acc.z += fb.x; acc.w += fb.y;
}

__device__ __forceinline__ Half4 to_h4(float x, float y, float z, float w) {
    Half4 h;
    h.a = __floats2half2_rn(x, y);
    h.b = __floats2half2_rn(z, w);
    return h;
}

// ---------------------------------------------------------------------------
// init: reservations + pad rows
// ---------------------------------------------------------------------------
__global__ void init_all(int* __restrict__ bcurU, int* __restrict__ bcurI,
                         __half* __restrict__ tauHall, __half* __restrict__ ybuf) {
    int t = threadIdx.x;
    for (int i = t; i < NBUCKU; i += 256) bcurU[i] = i * CAPU;
    for (int i = t; i < NBUCKI; i += 256) bcurI[i] = i * CAPI;
    if (t < BATCH) {
        for (int k = 0; k <= ORDER; ++k)
            tauHall[(size_t)k * SLOT + (size_t)NITEMS * BATCH + t] = __float2half(0.f);
        ybuf[(size_t)NUSERS * BATCH + t] = __float2half(0.f);
    }
}

// ---------------------------------------------------------------------------
// scatter1: 512 blocks x 1024 threads, 8 LDS sub-counters (R24, verified)
// ---------------------------------------------------------------------------
__global__ void scatter1(const int* __restrict__ row, const int* __restrict__ col,
                         int* __restrict__ bcurU, int* __restrict__ bcurI,
                         int* __restrict__ stU, int* __restrict__ stI, int nnz) {
    __shared__ int cU[NREP * NBUCKU];
    __shared__ int cI[NREP * NBUCKI];
    const int tid = threadIdx.x;
    const int chunk = (nnz + S1_BLOCKS - 1) / S1_BLOCKS;
    const int b0 = blockIdx.x * chunk;
    const int e0 = min(b0 + chunk, nnz);
    const int sw = S1_SW(tid);
    for (int t = tid; t < NREP * NBUCKU; t += S1_THREADS) cU[t] = 0;
    for (int t = tid; t < NREP * NBUCKI; t += S1_THREADS) cI[t] = 0;
    __syncthreads();
    for (int i = b0 + tid; i < e0; i += S1_THREADS) {
        atomicAdd(&cU[sw * NBUCKU + (row[i] >> BSHIFT)], 1);
        atomicAdd(&cI[sw * NBUCKI + (col[i] >> BSHIFT)], 1);
    }
    __syncthreads();
    for (int t = tid; t < NBUCKU; t += S1_THREADS) {
        int c[NREP], tot = 0;
        #pragma unroll
        for (int j = 0; j < NREP; ++j) { c[j] = cU[j * NBUCKU + t]; tot += c[j]; }
        int base = (tot > 0) ? atomicAdd(&bcurU[t], tot) : 0;
        #pragma unroll
        for (int j = 0; j < NREP; ++j) { cU[j * NBUCKU + t] = base; base += c[j]; }
    }
    for (int t = tid; t < NBUCKI; t += S1_THREADS) {
        int c[NREP], tot = 0;
        #pragma unroll
        for (int j = 0; j < NREP; ++j) { c[j] = cI[j * NBUCKI + t]; tot += c[j]; }
        int base = (tot > 0) ? atomicAdd(&bcurI[t], tot) : 0;
        #pragma unroll
        for (int j = 0; j < NREP; ++j) { cI[j * NBUCKI + t] = base; base += c[j]; }
    }
    __syncthreads();
    for (int i = b0 + tid; i < e0; i += S1_THREADS) {
        int r = row[i], c = col[i];
        int pu = atomicAdd(&cU[sw * NBUCKU + (r >> BSHIFT)], 1);
        stU[pu] = ((r & (BROWS - 1)) << 17) | c;
        int pi = atomicAdd(&cI[sw * NBUCKI + (c >> BSHIFT)], 1);
        stI[pi] = ((c & (BROWS - 1)) << 17) | r;
    }
}

// ---------------------------------------------------------------------------
// scatter2: 1024 threads/block, pad granularity 16
// ---------------------------------------------------------------------------
__device__ void scatter2_body(int bucket, const int* __restrict__ bcur,
                              const int* __restrict__ st, int* __restrict__ ptr,
                              int* __restrict__ degOut, int* __restrict__ outIdx,
                              int nrows, int cap, int dummyIdx, int* sm) {
    int* deg = sm;                      // BROWS
    int* ps  = sm + BROWS;              // 256
    int* cur = sm + BROWS + 256;        // BROWS
    int* rs  = sm + 2 * BROWS + 256;    // BROWS
    const int rbase = bucket << BSHIFT;
    const int nr = min(BROWS, nrows - rbase);
    const int lo = bucket * cap;
    const int hi = bcur[bucket];
    const int t = threadIdx.x;
    for (int i = t; i < BROWS; i += S2_THREADS) deg[i] = 0;
    __syncthreads();
    for (int j = lo + t; j < hi; j += S2_THREADS)
        atomicAdd(&deg[st[j] >> 17], 1);
    __syncthreads();
    int a = 0, b = 0, pa = 0, pb = 0;
    if (t < 256) {
        a = deg[2 * t];
        b = deg[2 * t + 1];
        pa = (a + 15) & ~15;
        pb = (b + 15) & ~15;
        ps[t] = pa + pb;
    }
    __syncthreads();
    for (int off = 1; off < 256; off <<= 1) {
        int u = (t >= off && t < 256) ? ps[t - off] : 0;
        __syncthreads();
        if (t < 256) ps[t] += u;
        __syncthreads();
    }
    if (t < 256) {
        int excl = (t > 0) ? ps[t - 1] : 0;
        int p0 = lo + excl;
        int p1 = p0 + pa;
        rs[2 * t] = p0;
        rs[2 * t + 1] = p1;
        cur[2 * t] = p0;
        cur[2 * t + 1] = p1;
        if (2 * t < nr)     { ptr[rbase + 2 * t] = p0;     degOut[rbase + 2 * t] = a; }
        if (2 * t + 1 < nr) { ptr[rbase + 2 * t + 1] = p1; degOut[rbase + 2 * t + 1] = b; }
    }
    __syncthreads();
    for (int j = lo + t; j < hi; j += S2_THREADS) {
        int v = st[j];
        int p = atomicAdd(&cur[v >> 17], 1);
        outIdx[p] = v & 0x1FFFF;
    }
    __syncthreads();
    for (int i = t; i < nr; i += S2_THREADS) {
        int endReal = cur[i];
        int endPad  = rs[i] + ((deg[i] + 15) & ~15);
        for (int j = endReal; j < endPad; ++j) outIdx[j] = dummyIdx;
    }
}

__global__ void scatter2_both(const int* __restrict__ bcurU, const int* __restrict__ stU,
                              int* __restrict__ uptr, int* __restrict__ udeg,
                              int* __restrict__ ucol,
                              const int* __restrict__ bcurI, const int* __restrict__ stI,
                              int* __restrict__ iptr, int* __restrict__ ideg,
                              int* __restrict__ irow) {
    __shared__ int sm[1792];
    if (blockIdx.x < NBUCKU)
        scatter2_body(blockIdx.x, bcurU, stU, uptr, udeg, ucol,
                      NUSERS, CAPU, NITEMS, sm);
    else
        scatter2_body(blockIdx.x - NBUCKU, bcurI, stI, iptr, ideg, irow,
                      NITEMS, CAPI, NUSERS, sm);
}

// ---------------------------------------------------------------------------
// transposes (R19, verified)
// ---------------------------------------------------------------------------
__global__ void transpose_scale_k(const float* __restrict__ in,
                                  const int* __restrict__ ideg,
                                  float* __restrict__ out,
                                  __half* __restrict__ outH) {
    __shared__ float tile[32][33];
    const int cb = blockIdx.x * 32;
    const int rb = blockIdx.y * 32;
    for (int i = threadIdx.y; i < 32; i += 8) {
        int r = rb + i, c = cb + threadIdx.x;
        if (r < BATCH && c < NITEMS) tile[i][threadIdx.x] = in[(size_t)r * NITEMS + c];
    }
    __syncthreads();
    for (int i = threadIdx.y; i < 32; i += 8) {
        int c = cb + i, r = rb + threadIdx.x;
        if (c < NITEMS && r < BATCH) {
            int d = ideg[c];
            float dis = (d > 0) ? rsqrtf((float)d) : 0.0f;
            float v = dis * tile[threadIdx.x][i];
            out[(size_t)c * BATCH + r] = v;
            outH[(size_t)c * BATCH + r] = __float2half(v);
        }
    }
}

__global__ void transpose_out_k(const __half* __restrict__ tauHall,
                                const float* __restrict__ signal,
                                const int* __restrict__ ideg, float csum, Coeffs cf,
                                float* __restrict__ out) {
    __shared__ float tile[32][33];
    const int cb = blockIdx.x * 32;
    const int rb = blockIdx.y * 32;
    for (int i = threadIdx.y; i < 32; i += 8) {
        int r = rb + i, c = cb + threadIdx.x;
        if (r < NITEMS && c < BATCH) {
            size_t base = (size_t)r * BATCH + c;
            float s = 0.f;
            #pragma unroll
            for (int k = 0; k <= ORDER; ++k)
                s += cf.v[k] * __half2float(tauHall[(size_t)k * SLOT + base]);
            tile[i][threadIdx.x] = s;
        }
    }
    __syncthreads();
    for (int i = threadIdx.y; i < 32; i += 8) {
        int c = cb + i, r = rb + threadIdx.x;
        if (c < BATCH && r < NITEMS) {
            int d = ideg[r];
            float v = (d > 0) ? sqrtf((float)d) * tile[threadIdx.x][i]
                              : csum * signal[(size_t)c * NITEMS + r];
            out[(size_t)c * NITEMS + r] = v;
        }
    }
}

// ---------------------------------------------------------------------------
// 4-row gather core, pad-16 + depth-1 idx prefetch + nontemporal idx stream.
// Iter it's gathers consume idx loaded at it-1; next idx issues concurrently
// with gathers. ext_vector types for the nontemporal builtins.
// ---------------------------------------------------------------------------
__device__ __forceinline__ void gather4_p(const int* __restrict__ idx,
                                          const Half4* __restrict__ x,
                                          const int* b, const int* n,
                                          int sub, int bh, float4* a) {
    const char* __restrict__ xb = (const char*)x;
    const char* __restrict__ ib = (const char*)idx;
    const unsigned bhoff = (unsigned)bh << 3;
    unsigned jb[4];
    iv4 ii[4];
    int nmax = 0;
    #pragma unroll
    for (int q = 0; q < 4; ++q) {
        jb[q] = ((unsigned)b[q] << 2) + ((unsigned)sub << 4);
        nmax = max(nmax, n[q]);
        ii[q] = __builtin_nontemporal_load((const iv4*)(ib + jb[q]));
    }
    for (int it = 0; it < nmax; ++it) {
        #pragma unroll
        for (int q = 0; q < 4; ++q) {
            iv4 cur = ii[q];
            jb[q] += 64;
            if (it + 1 < n[q])
                ii[q] = __builtin_nontemporal_load((const iv4*)(ib + jb[q]));
            if (it < n[q]) {
                Half4 v0 = *(const Half4*)(xb + (((unsigned)cur.x << 7) + bhoff));
                Half4 v1 = *(const Half4*)(xb + (((unsigned)cur.y << 7) + bhoff));
                Half4 v2 = *(const Half4*)(xb + (((unsigned)cur.z << 7) + bhoff));
                Half4 v3 = *(const Half4*)(xb + (((unsigned)cur.w << 7) + bhoff));
                acc_pk(a[q], v0, v1, v2, v3);
            }
        }
    }
    #pragma unroll
    for (int q = 0; q < 4; ++q) {
        a[q].x += __shfl_xor(a[q].x, 16); a[q].y += __shfl_xor(a[q].y, 16);
        a[q].z += __shfl_xor(a[q].z, 16); a[q].w += __shfl_xor(a[q].w, 16);
        a[q].x += __shfl_xor(a[q].x, 32); a[q].y += __shfl_xor(a[q].y, 32);
        a[q].z += __shfl_xor(a[q].z, 32); a[q].w += __shfl_xor(a[q].w, 32);
    }
}

__global__ void spmm_user(const int* __restrict__ ptr, const int* __restrict__ deg,
                          const int* __restrict__ idx,
                          const Half4* __restrict__ tauH, Half4* __restrict__ y) {
    const int lane = threadIdx.x & 63;
    const int w = (blockIdx.x * blockDim.x + threadIdx.x) >> 6;
    const int H = NUSERS / 4;
    if (w >= H) return;
    int r[4] = {w, w + H, w + 2 * H, w + 3 * H};
    const int sub = lane >> 4;
    const int bh  = lane & 15;
    int b[4], d[4], n[4];
    #pragma unroll
    for (int q = 0; q < 4; ++q) {
        b[q] = ptr[r[q]];
        d[q] = deg[r[q]];
        n[q] = (d[q] + 15) >> 4;
    }
    float4 a[4] = {{0,0,0,0},{0,0,0,0},{0,0,0,0},{0,0,0,0}};
    gather4_p(idx, tauH, b, n, sub, bh, a);
    if (sub == 0) {
        #pragma unroll
        for (int q = 0; q < 4; ++q) {
            float s = (d[q] > 0) ? 1.0f / (float)d[q] : 0.0f;
            y[(size_t)r[q] * 16 + bh] = to_h4(s * a[q].x, s * a[q].y, s * a[q].z, s * a[q].w);
        }
    }
}

__global__ void spmm_item_first(const int* __restrict__ ptr, const int* __restrict__ deg,
                                const int* __restrict__ idx, const Half4* __restrict__ y,
                                const float* __restrict__ tau0, float* __restrict__ tau1,
                                Half4* __restrict__ tauH1) {
    const int lane = threadIdx.x & 63;
    const int w = (blockIdx.x * blockDim.x + threadIdx.x) >> 6;
    const int H = NITEMS / 4;
    if (w >= H) return;
    int r[4] = {w, w + H, w + 2 * H, w + 3 * H};
    const int sub = lane >> 4;
    const int bh  = lane & 15;
    int b[4], d[4], n[4];
    #pragma unroll
    for (int q = 0; q < 4; ++q) {
        b[q] = ptr[r[q]];
        d[q] = deg[r[q]];
        n[q] = (d[q] + 15) >> 4;
    }
    float4 a[4] = {{0,0,0,0},{0,0,0,0},{0,0,0,0},{0,0,0,0}};
    gather4_p(idx, y, b, n, sub, bh, a);
    if (sub == 0) {
        #pragma unroll
        for (int q = 0; q < 4; ++q) {
            float inv = (d[q] > 0) ? 1.0f / (float)d[q] : 0.0f;
            float s2 = 2.0f * inv;
            size_t base = (size_t)r[q] * BATCH + (bh << 2);
            fv4 t0v = __builtin_nontemporal_load((const fv4*)&tau0[base]);
            fv4 t;
            t.x = t0v.x - s2 * a[q].x; t.y = t0v.y - s2 * a[q].y;
            t.z = t0v.z - s2 * a[q].z; t.w = t0v.w - s2 * a[q].w;
            __builtin_nontemporal_store(t, (fv4*)&tau1[base]);
            tauH1[(size_t)r[q] * 16 + bh] = to_h4(t.x, t.y, t.z, t.w);
        }
    }
}

__global__ void spmm_item_k(const int* __restrict__ ptr, const int* __restrict__ deg,
                            const int* __restrict__ idx, const Half4* __restrict__ y,
                            const float* __restrict__ tau1, float* __restrict__ tau0,
                            Half4* __restrict__ tauHk) {
    const int lane = threadIdx.x & 63;
    const int w = (blockIdx.x * blockDim.x + threadIdx.x) >> 6;
    const int H = NITEMS / 4;
    if (w >= H) return;
    int r[4] = {w, w + H, w + 2 * H, w + 3 * H};
    const int sub = lane >> 4;
    const int bh  = lane & 15;
    int b[4], d[4], n[4];
    #pragma unroll
    for (int q = 0; q < 4; ++q) {
        b[q] = ptr[r[q]];
        d[q] = deg[r[q]];
        n[q] = (d[q] + 15) >> 4;
    }
    float4 a[4] = {{0,0,0,0},{0,0,0,0},{0,0,0,0},{0,0,0,0}};
    gather4_p(idx, y, b, n, sub, bh, a);
    if (sub == 0) {
        #pragma unroll
        for (int q = 0; q < 4; ++q) {
            float inv = (d[q] > 0) ? 1.0f / (float)d[q] : 0.0f;
            float s4 = 4.0f * inv;
            size_t base = (size_t)r[q] * BATCH + (bh << 2);
            fv4 t1v = __builtin_nontemporal_load((const fv4*)&tau1[base]);
            fv4 t0v = __builtin_nontemporal_load((const fv4*)&tau0[base]);
            fv4 t2;
            t2.x = 2.0f * t1v.x - s4 * a[q].x - t0v.x;
            t2.y = 2.0f * t1v.y - s4 * a[q].y - t0v.y;
            t2.z = 2.0f * t1v.z - s4 * a[q].z - t0v.z;
            t2.w = 2.0f * t1v.w - s4 * a[q].w - t0v.w;
            __builtin_nontemporal_store(t2, (fv4*)&tau0[base]);
            tauHk[(size_t)r[q] * 16 + bh] = to_h4(t2.x, t2.y, t2.z, t2.w);
        }
    }
}

// ---------------------------------------------------------------------------
// Host-side exact replica of reference cheby_coeffs
// ---------------------------------------------------------------------------
static void cheby_coeffs_host(float* c) {
    const int order = ORDER, flatness = 2;
    const double PI = 3.14159265358979323846;
    double tgt[ORDER + 1], nodes[ORDER + 1];
    for (int x = 0; x <= order; ++x) {
        double xv = cos((double)(order - x) / order * PI);
        xv = nearbyint(xv * 1000.0) / 1000.0;
        double t = (xv < 0.0) ? pow(-xv, (double)flatness) * 0.5 + 0.5
                              : pow(xv, (double)flatness) * (-0.5) + 0.5;
        tgt[x] = nearbyint(t * 1000.0) / 1000.0;
    }
    for (int k = 1; k <= order + 1; ++k)
        nodes[k - 1] = cos((order + 1 + 0.5 - k) / (double)(order + 1) * PI);

    double prev[ORDER + 1], cur[ORDER + 1], nxt[ORDER + 1];
    double sums[ORDER + 1];
    double s0 = 0, s1 = 0;
    for (int i = 0; i <= order; ++i) {
        prev[i] = tgt[i];
        cur[i]  = nodes[i] * tgt[i];
        s0 += prev[i];
        s1 += cur[i];
    }
    sums[0] = s0; sums[1] = s1;
    for (int j = 2; j <= order; ++j) {
        double s = 0;
        for (int i = 0; i <= order; ++i) {
            nxt[i] = nodes[i] * cur[i] * 2.0 - prev[i];
            s += nxt[i];
        }
        sums[j] = s;
        for (int i = 0; i <= order; ++i) { prev[i] = cur[i]; cur[i] = nxt[i]; }
    }
    for (int j = 0; j <= order; ++j)
        c[j] = (float)(sums[j] * (2.0 / (order + 1)));
    c[0] *= 0.5f;
}

extern "C" void kernel_launch(void* const* d_in, const int* in_sizes, int n_in,
                              void* d_out, int out_size, void* d_ws, size_t ws_size,
                              hipStream_t stream) {
    const float* signal = (const float*)d_in[0];   // [BATCH, NITEMS]
    const int*   row    = (const int*)d_in[2];     // [NNZ] -> users
    const int*   col    = (const int*)d_in[3];     // [NNZ] -> items
    const int nnz = in_sizes[1];

    char* wsb = (char*)d_ws;
    size_t off = 0;
    auto carve = [&](size_t nbytes) {
        void* p = wsb + off;
        off += (nbytes + 255) & ~(size_t)255;
        return p;
    };
    const size_t NB = (size_t)NITEMS * BATCH;
    const size_t NEU = (size_t)NBUCKU * CAPU;
    const size_t NEI = (size_t)NBUCKI * CAPI;
    float*  tauA   = (float*)carve(NB * 4);
    float*  tauB   = (float*)carve(NB * 4);
    __half* tauHall = (__half*)carve((ORDER + 1) * SLOT * 2);
    Half4*  ybuf   = (Half4*)carve(((size_t)NUSERS + 1) * BATCH * 2);
    int*    uptr   = (int*)carve(NUSERS * 4);
    int*    iptr   = (int*)carve(NITEMS * 4);
    int*    udeg   = (int*)carve(NUSERS * 4);
    int*    ideg   = (int*)carve(NITEMS * 4);
    int*    bcurU  = (int*)carve(NBUCKU * 4);
    int*    bcurI  = (int*)carve(NBUCKI * 4);
    int*    ucol   = (int*)carve(NEU * 4 + 256);
    int*    irow   = (int*)carve(NEI * 4 + 256);
    int*    stU    = (int*)carve(NEU * 4);       // separate carve: no aliasing
    int*    stI    = (int*)carve(NEI * 4);
    (void)ws_size;

    float c[ORDER + 1];
    cheby_coeffs_host(c);
    Coeffs cf;
    float csum = 0.f;
    for (int k = 0; k <= ORDER; ++k) { cf.v[k] = c[k]; csum += c[k]; }

    // ---- CSR build ----
    init_all<<<1, 256, 0, stream>>>(bcurU, bcurI, tauHall, (__half*)ybuf);
    scatter1<<<S1_BLOCKS, S1_THREADS, 0, stream>>>(row, col, bcurU, bcurI, stU, stI, nnz);
    scatter2_both<<<NBUCKU + NBUCKI, S2_THREADS, 0, stream>>>(bcurU, stU, uptr, udeg, ucol,
                                                              bcurI, stI, iptr, ideg, irow);

    // ---- tau0 (fp32 + fp16 slot 0) ----
    dim3 tb(32, 8);
    transpose_scale_k<<<dim3((NITEMS + 31) / 32, (BATCH + 31) / 32), tb, 0, stream>>>(
        signal, ideg, tauA, tauHall);

    const int ug = ((NUSERS / 4) * 64 + 255) / 256;   // user: 4 rows/wave (padded)
    const int ig = ((NITEMS / 4) * 64 + 255) / 256;   // item: 4 rows/wave

    // ---- k = 1 ----
    spmm_user<<<ug, 256, 0, stream>>>(uptr, udeg, ucol, (const Half4*)tauHall, ybuf);
    spmm_item_first<<<ig, 256, 0, stream>>>(iptr, ideg, irow, ybuf, tauA, tauB,
                                            (Half4*)(tauHall + SLOT));

    float* t0 = tauA;
    float* t1 = tauB;
    for (int k = 2; k <= ORDER; ++k) {
        spmm_user<<<ug, 256, 0, stream>>>(uptr, udeg, ucol,
                                          (const Half4*)(tauHall + (size_t)(k - 1) * SLOT), ybuf);
        spmm_item_k<<<ig, 256, 0, stream>>>(iptr, ideg, irow, ybuf, t1, t0,
                                            (Half4*)(tauHall + (size_t)k * SLOT));
        float* tmp = t0; t0 = t1; t1 = tmp;
    }

    // ---- d_out = sqrt(di) * sum_k c_k tauH_k, transposed ----
    transpose_out_k<<<dim3((BATCH + 31) / 32, (NITEMS + 31) / 32), tb, 0, stream>>>(
        tauHall, signal, ideg, csum, cf, (float*)d_out);
}

// Round 14
// 694.795 us; speedup vs baseline: 1.1505x; 1.1505x over previous
//
#include <hip/hip_runtime.h>
#include <hip/hip_fp16.h>
#include <math.h>

#define NUSERS 100000
#define NITEMS 50000
#define BATCH  64
#define ORDER  8
#define BSHIFT 9                                   // 512 rows per bucket
#define BROWS  (1 << BSHIFT)
#define NBUCKU ((NUSERS + BROWS - 1) >> BSHIFT)    // 196
#define NBUCKI ((NITEMS + BROWS - 1) >> BSHIFT)    // 98
#define CAPU 16384
#define CAPI 24576
#define S1_BLOCKS 512
#define S1_THREADS 1024
#define NREP 8
#define S1_SW(t) (((t) >> 6) & (NREP - 1))
#define S2_THREADS 1024

// ---------------------------------------------------------------------------
// R30: R29 (prefetch+NT) regressed 711->799 and completed the diagnosis:
// NT barely moved FETCH (96.5->92.9), prefetch cost occupancy (VGPR 28->44,
// 56.7->37.5%) and time. Across variants time == hbm_bytes / ~2.6 TB/s ->
// HARD FILL-BOUND at the random-gather HBM efficiency ceiling (~40% of
// streaming peak; issue-rate is <0.5/cyc/CU, not TA-bound). Only lever:
// cut hbm_bytes. The fp16 tauHall slots already hold the full recurrence
// state -> drop the fp32 tauA/tauB entirely; spmm_item reads slots k-1,k-2
// (12.8MB fp16 vs 25.6 fp32) and writes slot k (6.4 vs 19.2). Gather core
// reverted to R25's proven form (VGPR 28). Risk: fp16 state raises absmax
// ~0.002 -> est 0.004-0.008 (stable recurrence, ~sqrt(k) growth); if the
// harness rejects, revert to R25 + declare roofline. Predict: item 42.5->
// ~33us (FETCH ->~80MB, WRITE ->~6.5MB, fill-rate unchanged), total 711 ->
// ~635-660us.
// ---------------------------------------------------------------------------

struct __align__(8) Half4 { __half2 a, b; };
struct Coeffs { float v[ORDER + 1]; };

#define SLOT ((size_t)(NITEMS + 1) * BATCH)        // fp16 tau slot incl. zero row

__device__ __forceinline__ void acc_pk(float4& acc, Half4 v0, Half4 v1,
                                       Half4 v2, Half4 v3) {
    __half2 sa = __hadd2(__hadd2(v0.a, v1.a), __hadd2(v2.a, v3.a));
    __half2 sb = __hadd2(__hadd2(v0.b, v1.b), __hadd2(v2.b, v3.b));
    float2 fa = __half22float2(sa);
    float2 fb = __half22float2(sb);
    acc.x += fa.x; acc.y += fa.y; acc.z += fb.x; acc.w += fb.y;
}

__device__ __forceinline__ Half4 to_h4(float x, float y, float z, float w) {
    Half4 h;
    h.a = __floats2half2_rn(x, y);
    h.b = __floats2half2_rn(z, w);
    return h;
}

__device__ __forceinline__ float4 h4_to_f4(Half4 h) {
    float2 a = __half22float2(h.a);
    float2 b = __half22float2(h.b);
    return make_float4(a.x, a.y, b.x, b.y);
}

// ---------------------------------------------------------------------------
// init: reservations + pad rows
// ---------------------------------------------------------------------------
__global__ void init_all(int* __restrict__ bcurU, int* __restrict__ bcurI,
                         __half* __restrict__ tauHall, __half* __restrict__ ybuf) {
    int t = threadIdx.x;
    for (int i = t; i < NBUCKU; i += 256) bcurU[i] = i * CAPU;
    for (int i = t; i < NBUCKI; i += 256) bcurI[i] = i * CAPI;
    if (t < BATCH) {
        for (int k = 0; k <= ORDER; ++k)
            tauHall[(size_t)k * SLOT + (size_t)NITEMS * BATCH + t] = __float2half(0.f);
        ybuf[(size_t)NUSERS * BATCH + t] = __float2half(0.f);
    }
}

// ---------------------------------------------------------------------------
// scatter1: 512 blocks x 1024 threads, 8 LDS sub-counters (R24, verified)
// ---------------------------------------------------------------------------
__global__ void scatter1(const int* __restrict__ row, const int* __restrict__ col,
                         int* __restrict__ bcurU, int* __restrict__ bcurI,
                         int* __restrict__ stU, int* __restrict__ stI, int nnz) {
    __shared__ int cU[NREP * NBUCKU];
    __shared__ int cI[NREP * NBUCKI];
    const int tid = threadIdx.x;
    const int chunk = (nnz + S1_BLOCKS - 1) / S1_BLOCKS;
    const int b0 = blockIdx.x * chunk;
    const int e0 = min(b0 + chunk, nnz);
    const int sw = S1_SW(tid);
    for (int t = tid; t < NREP * NBUCKU; t += S1_THREADS) cU[t] = 0;
    for (int t = tid; t < NREP * NBUCKI; t += S1_THREADS) cI[t] = 0;
    __syncthreads();
    for (int i = b0 + tid; i < e0; i += S1_THREADS) {
        atomicAdd(&cU[sw * NBUCKU + (row[i] >> BSHIFT)], 1);
        atomicAdd(&cI[sw * NBUCKI + (col[i] >> BSHIFT)], 1);
    }
    __syncthreads();
    for (int t = tid; t < NBUCKU; t += S1_THREADS) {
        int c[NREP], tot = 0;
        #pragma unroll
        for (int j = 0; j < NREP; ++j) { c[j] = cU[j * NBUCKU + t]; tot += c[j]; }
        int base = (tot > 0) ? atomicAdd(&bcurU[t], tot) : 0;
        #pragma unroll
        for (int j = 0; j < NREP; ++j) { cU[j * NBUCKU + t] = base; base += c[j]; }
    }
    for (int t = tid; t < NBUCKI; t += S1_THREADS) {
        int c[NREP], tot = 0;
        #pragma unroll
        for (int j = 0; j < NREP; ++j) { c[j] = cI[j * NBUCKI + t]; tot += c[j]; }
        int base = (tot > 0) ? atomicAdd(&bcurI[t], tot) : 0;
        #pragma unroll
        for (int j = 0; j < NREP; ++j) { cI[j * NBUCKI + t] = base; base += c[j]; }
    }
    __syncthreads();
    for (int i = b0 + tid; i < e0; i += S1_THREADS) {
        int r = row[i], c = col[i];
        int pu = atomicAdd(&cU[sw * NBUCKU + (r >> BSHIFT)], 1);
        stU[pu] = ((r & (BROWS - 1)) << 17) | c;
        int pi = atomicAdd(&cI[sw * NBUCKI + (c >> BSHIFT)], 1);
        stI[pi] = ((c & (BROWS - 1)) << 17) | r;
    }
}

// ---------------------------------------------------------------------------
// scatter2: 1024 threads/block, pad granularity 16 (R25, verified)
// ---------------------------------------------------------------------------
__device__ void scatter2_body(int bucket, const int* __restrict__ bcur,
                              const int* __restrict__ st, int* __restrict__ ptr,
                              int* __restrict__ degOut, int* __restrict__ outIdx,
                              int nrows, int cap, int dummyIdx, int* sm) {
    int* deg = sm;                      // BROWS
    int* ps  = sm + BROWS;              // 256
    int* cur = sm + BROWS + 256;        // BROWS
    int* rs  = sm + 2 * BROWS + 256;    // BROWS
    const int rbase = bucket << BSHIFT;
    const int nr = min(BROWS, nrows - rbase);
    const int lo = bucket * cap;
    const int hi = bcur[bucket];
    const int t = threadIdx.x;
    for (int i = t; i < BROWS; i += S2_THREADS) deg[i] = 0;
    __syncthreads();
    for (int j = lo + t; j < hi; j += S2_THREADS)
        atomicAdd(&deg[st[j] >> 17], 1);
    __syncthreads();
    int a = 0, b = 0, pa = 0, pb = 0;
    if (t < 256) {
        a = deg[2 * t];
        b = deg[2 * t + 1];
        pa = (a + 15) & ~15;
        pb = (b + 15) & ~15;
        ps[t] = pa + pb;
    }
    __syncthreads();
    for (int off = 1; off < 256; off <<= 1) {
        int u = (t >= off && t < 256) ? ps[t - off] : 0;
        __syncthreads();
        if (t < 256) ps[t] += u;
        __syncthreads();
    }
    if (t < 256) {
        int excl = (t > 0) ? ps[t - 1] : 0;
        int p0 = lo + excl;
        int p1 = p0 + pa;
        rs[2 * t] = p0;
        rs[2 * t + 1] = p1;
        cur[2 * t] = p0;
        cur[2 * t + 1] = p1;
        if (2 * t < nr)     { ptr[rbase + 2 * t] = p0;     degOut[rbase + 2 * t] = a; }
        if (2 * t + 1 < nr) { ptr[rbase + 2 * t + 1] = p1; degOut[rbase + 2 * t + 1] = b; }
    }
    __syncthreads();
    for (int j = lo + t; j < hi; j += S2_THREADS) {
        int v = st[j];
        int p = atomicAdd(&cur[v >> 17], 1);
        outIdx[p] = v & 0x1FFFF;
    }
    __syncthreads();
    for (int i = t; i < nr; i += S2_THREADS) {
        int endReal = cur[i];
        int endPad  = rs[i] + ((deg[i] + 15) & ~15);
        for (int j = endReal; j < endPad; ++j) outIdx[j] = dummyIdx;
    }
}

__global__ void scatter2_both(const int* __restrict__ bcurU, const int* __restrict__ stU,
                              int* __restrict__ uptr, int* __restrict__ udeg,
                              int* __restrict__ ucol,
                              const int* __restrict__ bcurI, const int* __restrict__ stI,
                              int* __restrict__ iptr, int* __restrict__ ideg,
                              int* __restrict__ irow) {
    __shared__ int sm[1792];
    if (blockIdx.x < NBUCKU)
        scatter2_body(blockIdx.x, bcurU, stU, uptr, udeg, ucol,
                      NUSERS, CAPU, NITEMS, sm);
    else
        scatter2_body(blockIdx.x - NBUCKU, bcurI, stI, iptr, ideg, irow,
                      NITEMS, CAPI, NUSERS, sm);
}

// ---------------------------------------------------------------------------
// transposes: tau0 now fp16-only (no fp32 mirror)
// ---------------------------------------------------------------------------
__global__ void transpose_scale_k(const float* __restrict__ in,
                                  const int* __restrict__ ideg,
                                  __half* __restrict__ outH) {
    __shared__ float tile[32][33];
    const int cb = blockIdx.x * 32;
    const int rb = blockIdx.y * 32;
    for (int i = threadIdx.y; i < 32; i += 8) {
        int r = rb + i, c = cb + threadIdx.x;
        if (r < BATCH && c < NITEMS) tile[i][threadIdx.x] = in[(size_t)r * NITEMS + c];
    }
    __syncthreads();
    for (int i = threadIdx.y; i < 32; i += 8) {
        int c = cb + i, r = rb + threadIdx.x;
        if (c < NITEMS && r < BATCH) {
            int d = ideg[c];
            float dis = (d > 0) ? rsqrtf((float)d) : 0.0f;
            float v = dis * tile[threadIdx.x][i];
            outH[(size_t)c * BATCH + r] = __float2half(v);
        }
    }
}

__global__ void transpose_out_k(const __half* __restrict__ tauHall,
                                const float* __restrict__ signal,
                                const int* __restrict__ ideg, float csum, Coeffs cf,
                                float* __restrict__ out) {
    __shared__ float tile[32][33];
    const int cb = blockIdx.x * 32;
    const int rb = blockIdx.y * 32;
    for (int i = threadIdx.y; i < 32; i += 8) {
        int r = rb + i, c = cb + threadIdx.x;
        if (r < NITEMS && c < BATCH) {
            size_t base = (size_t)r * BATCH + c;
            float s = 0.f;
            #pragma unroll
            for (int k = 0; k <= ORDER; ++k)
                s += cf.v[k] * __half2float(tauHall[(size_t)k * SLOT + base]);
            tile[i][threadIdx.x] = s;
        }
    }
    __syncthreads();
    for (int i = threadIdx.y; i < 32; i += 8) {
        int c = cb + i, r = rb + threadIdx.x;
        if (c < BATCH && r < NITEMS) {
            int d = ideg[r];
            float v = (d > 0) ? sqrtf((float)d) * tile[threadIdx.x][i]
                              : csum * signal[(size_t)c * NITEMS + r];
            out[(size_t)c * NITEMS + r] = v;
        }
    }
}

// ---------------------------------------------------------------------------
// R25 gather core (verified, VGPR 28): int4 idx loads + 32-bit byte offsets.
// ---------------------------------------------------------------------------
__device__ __forceinline__ void gather4_p(const int* __restrict__ idx,
                                          const Half4* __restrict__ x,
                                          const int* b, const int* n,
                                          int sub, int bh, float4* a) {
    const char* __restrict__ xb = (const char*)x;
    const char* __restrict__ ib = (const char*)idx;
    const unsigned bhoff = (unsigned)bh << 3;
    unsigned jb[4];
    int nmax = 0;
    #pragma unroll
    for (int q = 0; q < 4; ++q) {
        jb[q] = ((unsigned)b[q] << 2) + ((unsigned)sub << 4);
        nmax = max(nmax, n[q]);
    }
    for (int it = 0; it < nmax; ++it) {
        #pragma unroll
        for (int q = 0; q < 4; ++q) {
            if (it < n[q]) {
                int4 ii = *(const int4*)(ib + jb[q]);
                Half4 v0 = *(const Half4*)(xb + (((unsigned)ii.x << 7) + bhoff));
                Half4 v1 = *(const Half4*)(xb + (((unsigned)ii.y << 7) + bhoff));
                Half4 v2 = *(const Half4*)(xb + (((unsigned)ii.z << 7) + bhoff));
                Half4 v3 = *(const Half4*)(xb + (((unsigned)ii.w << 7) + bhoff));
                acc_pk(a[q], v0, v1, v2, v3);
                jb[q] += 64;
            }
        }
    }
    #pragma unroll
    for (int q = 0; q < 4; ++q) {
        a[q].x += __shfl_xor(a[q].x, 16); a[q].y += __shfl_xor(a[q].y, 16);
        a[q].z += __shfl_xor(a[q].z, 16); a[q].w += __shfl_xor(a[q].w, 16);
        a[q].x += __shfl_xor(a[q].x, 32); a[q].y += __shfl_xor(a[q].y, 32);
        a[q].z += __shfl_xor(a[q].z, 32); a[q].w += __shfl_xor(a[q].w, 32);
    }
}

__global__ void spmm_user(const int* __restrict__ ptr, const int* __restrict__ deg,
                          const int* __restrict__ idx,
                          const Half4* __restrict__ tauH, Half4* __restrict__ y) {
    const int lane = threadIdx.x & 63;
    const int w = (blockIdx.x * blockDim.x + threadIdx.x) >> 6;
    const int H = NUSERS / 4;
    if (w >= H) return;
    int r[4] = {w, w + H, w + 2 * H, w + 3 * H};
    const int sub = lane >> 4;
    const int bh  = lane & 15;
    int b[4], d[4], n[4];
    #pragma unroll
    for (int q = 0; q < 4; ++q) {
        b[q] = ptr[r[q]];
        d[q] = deg[r[q]];
        n[q] = (d[q] + 15) >> 4;
    }
    float4 a[4] = {{0,0,0,0},{0,0,0,0},{0,0,0,0},{0,0,0,0}};
    gather4_p(idx, tauH, b, n, sub, bh, a);
    if (sub == 0) {
        #pragma unroll
        for (int q = 0; q < 4; ++q) {
            float s = (d[q] > 0) ? 1.0f / (float)d[q] : 0.0f;
            y[(size_t)r[q] * 16 + bh] = to_h4(s * a[q].x, s * a[q].y, s * a[q].z, s * a[q].w);
        }
    }
}

// item, first step: tau1 = tau0 - (2/deg)*z ; fp16 state only
__global__ void spmm_item_first(const int* __restrict__ ptr, const int* __restrict__ deg,
                                const int* __restrict__ idx, const Half4* __restrict__ y,
                                const Half4* __restrict__ tauH0, Half4* __restrict__ tauH1) {
    const int lane = threadIdx.x & 63;
    const int w = (blockIdx.x * blockDim.x + threadIdx.x) >> 6;
    const int H = NITEMS / 4;
    if (w >= H) return;
    int r[4] = {w, w + H, w + 2 * H, w + 3 * H};
    const int sub = lane >> 4;
    const int bh  = lane & 15;
    int b[4], d[4], n[4];
    #pragma unroll
    for (int q = 0; q < 4; ++q) {
        b[q] = ptr[r[q]];
        d[q] = deg[r[q]];
        n[q] = (d[q] + 15) >> 4;
    }
    float4 a[4] = {{0,0,0,0},{0,0,0,0},{0,0,0,0},{0,0,0,0}};
    gather4_p(idx, y, b, n, sub, bh, a);
    if (sub == 0) {
        #pragma unroll
        for (int q = 0; q < 4; ++q) {
            float inv = (d[q] > 0) ? 1.0f / (float)d[q] : 0.0f;
            float s2 = 2.0f * inv;
            size_t base = (size_t)r[q] * 16 + bh;
            float4 t0v = h4_to_f4(tauH0[base]);
            tauH1[base] = to_h4(t0v.x - s2 * a[q].x, t0v.y - s2 * a[q].y,
                                t0v.z - s2 * a[q].z, t0v.w - s2 * a[q].w);
        }
    }
}

// item, general step: t2 = 2*t1 - (4/deg)*z - t0 ; fp16 state only
__global__ void spmm_item_k(const int* __restrict__ ptr, const int* __restrict__ deg,
                            const int* __restrict__ idx, const Half4* __restrict__ y,
                            const Half4* __restrict__ tauHm1,   // slot k-1 (t1)
                            const Half4* __restrict__ tauHm2,   // slot k-2 (t0)
                            Half4* __restrict__ tauHk) {        // slot k (out)
    const int lane = threadIdx.x & 63;
    const int w = (blockIdx.x * blockDim.x + threadIdx.x) >> 6;
    const int H = NITEMS / 4;
    if (w >= H) return;
    int r[4] = {w, w + H, w + 2 * H, w + 3 * H};
    const int sub = lane >> 4;
    const int bh  = lane & 15;
    int b[4], d[4], n[4];
    #pragma unroll
    for (int q = 0; q < 4; ++q) {
        b[q] = ptr[r[q]];
        d[q] = deg[r[q]];
        n[q] = (d[q] + 15) >> 4;
    }
    float4 a[4] = {{0,0,0,0},{0,0,0,0},{0,0,0,0},{0,0,0,0}};
    gather4_p(idx, y, b, n, sub, bh, a);
    if (sub == 0) {
        #pragma unroll
        for (int q = 0; q < 4; ++q) {
            float inv = (d[q] > 0) ? 1.0f / (float)d[q] : 0.0f;
            float s4 = 4.0f * inv;
            size_t base = (size_t)r[q] * 16 + bh;
            float4 t1v = h4_to_f4(tauHm1[base]);
            float4 t0v = h4_to_f4(tauHm2[base]);
            tauHk[base] = to_h4(2.0f * t1v.x - s4 * a[q].x - t0v.x,
                                2.0f * t1v.y - s4 * a[q].y - t0v.y,
                                2.0f * t1v.z - s4 * a[q].z - t0v.z,
                                2.0f * t1v.w - s4 * a[q].w - t0v.w);
        }
    }
}

// ---------------------------------------------------------------------------
// Host-side exact replica of reference cheby_coeffs
// ---------------------------------------------------------------------------
static void cheby_coeffs_host(float* c) {
    const int order = ORDER, flatness = 2;
    const double PI = 3.14159265358979323846;
    double tgt[ORDER + 1], nodes[ORDER + 1];
    for (int x = 0; x <= order; ++x) {
        double xv = cos((double)(order - x) / order * PI);
        xv = nearbyint(xv * 1000.0) / 1000.0;
        double t = (xv < 0.0) ? pow(-xv, (double)flatness) * 0.5 + 0.5
                              : pow(xv, (double)flatness) * (-0.5) + 0.5;
        tgt[x] = nearbyint(t * 1000.0) / 1000.0;
    }
    for (int k = 1; k <= order + 1; ++k)
        nodes[k - 1] = cos((order + 1 + 0.5 - k) / (double)(order + 1) * PI);

    double prev[ORDER + 1], cur[ORDER + 1], nxt[ORDER + 1];
    double sums[ORDER + 1];
    double s0 = 0, s1 = 0;
    for (int i = 0; i <= order; ++i) {
        prev[i] = tgt[i];
        cur[i]  = nodes[i] * tgt[i];
        s0 += prev[i];
        s1 += cur[i];
    }
    sums[0] = s0; sums[1] = s1;
    for (int j = 2; j <= order; ++j) {
        double s = 0;
        for (int i = 0; i <= order; ++i) {
            nxt[i] = nodes[i] * cur[i] * 2.0 - prev[i];
            s += nxt[i];
        }
        sums[j] = s;
        for (int i = 0; i <= order; ++i) { prev[i] = cur[i]; cur[i] = nxt[i]; }
    }
    for (int j = 0; j <= order; ++j)
        c[j] = (float)(sums[j] * (2.0 / (order + 1)));
    c[0] *= 0.5f;
}

extern "C" void kernel_launch(void* const* d_in, const int* in_sizes, int n_in,
                              void* d_out, int out_size, void* d_ws, size_t ws_size,
                              hipStream_t stream) {
    const float* signal = (const float*)d_in[0];   // [BATCH, NITEMS]
    const int*   row    = (const int*)d_in[2];     // [NNZ] -> users
    const int*   col    = (const int*)d_in[3];     // [NNZ] -> items
    const int nnz = in_sizes[1];

    char* wsb = (char*)d_ws;
    size_t off = 0;
    auto carve = [&](size_t nbytes) {
        void* p = wsb + off;
        off += (nbytes + 255) & ~(size_t)255;
        return p;
    };
    const size_t NEU = (size_t)NBUCKU * CAPU;
    const size_t NEI = (size_t)NBUCKI * CAPI;
    __half* tauHall = (__half*)carve((ORDER + 1) * SLOT * 2);
    Half4*  ybuf   = (Half4*)carve(((size_t)NUSERS + 1) * BATCH * 2);
    int*    uptr   = (int*)carve(NUSERS * 4);
    int*    iptr   = (int*)carve(NITEMS * 4);
    int*    udeg   = (int*)carve(NUSERS * 4);
    int*    ideg   = (int*)carve(NITEMS * 4);
    int*    bcurU  = (int*)carve(NBUCKU * 4);
    int*    bcurI  = (int*)carve(NBUCKI * 4);
    int*    ucol   = (int*)carve(NEU * 4);
    int*    irow   = (int*)carve(NEI * 4);
    int*    stU    = (int*)carve(NEU * 4);       // separate carve: no aliasing
    int*    stI    = (int*)carve(NEI * 4);
    (void)ws_size;

    float c[ORDER + 1];
    cheby_coeffs_host(c);
    Coeffs cf;
    float csum = 0.f;
    for (int k = 0; k <= ORDER; ++k) { cf.v[k] = c[k]; csum += c[k]; }

    // ---- CSR build ----
    init_all<<<1, 256, 0, stream>>>(bcurU, bcurI, tauHall, (__half*)ybuf);
    scatter1<<<S1_BLOCKS, S1_THREADS, 0, stream>>>(row, col, bcurU, bcurI, stU, stI, nnz);
    scatter2_both<<<NBUCKU + NBUCKI, S2_THREADS, 0, stream>>>(bcurU, stU, uptr, udeg, ucol,
                                                              bcurI, stI, iptr, ideg, irow);

    // ---- tau0 (fp16 slot 0 only) ----
    dim3 tb(32, 8);
    transpose_scale_k<<<dim3((NITEMS + 31) / 32, (BATCH + 31) / 32), tb, 0, stream>>>(
        signal, ideg, tauHall);

    const int ug = ((NUSERS / 4) * 64 + 255) / 256;   // user: 4 rows/wave (padded)
    const int ig = ((NITEMS / 4) * 64 + 255) / 256;   // item: 4 rows/wave

    // ---- k = 1 ----
    spmm_user<<<ug, 256, 0, stream>>>(uptr, udeg, ucol, (const Half4*)tauHall, ybuf);
    spmm_item_first<<<ig, 256, 0, stream>>>(iptr, ideg, irow, ybuf,
                                            (const Half4*)tauHall,
                                            (Half4*)(tauHall + SLOT));

    for (int k = 2; k <= ORDER; ++k) {
        spmm_user<<<ug, 256, 0, stream>>>(uptr, udeg, ucol,
                                          (const Half4*)(tauHall + (size_t)(k - 1) * SLOT), ybuf);
        spmm_item_k<<<ig, 256, 0, stream>>>(iptr, ideg, irow, ybuf,
                                            (const Half4*)(tauHall + (size_t)(k - 1) * SLOT),
                                            (const Half4*)(tauHall + (size_t)(k - 2) * SLOT),
                                            (Half4*)(tauHall + (size_t)k * SLOT));
    }

    // ---- d_out = sqrt(di) * sum_k c_k tauH_k, transposed ----
    transpose_out_k<<<dim3((BATCH + 31) / 32, (NITEMS + 31) / 32), tb, 0, stream>>>(
        tauHall, signal, ideg, csum, cf, (float*)d_out);
}